// Round 1
// baseline (2083.206 us; speedup 1.0000x reference)
//
#include <hip/hip_runtime.h>
#include <math.h>

#define BB 4
#define TT 4096
#define DD 1024
#define FF 4096
#define NHH 16
#define HDD 64
#define KSEL 512
#define BT (BB*TT)        // 16384
#define MTOK (BB*KSEL)    // 2048

// ---------------- scores: one wave per row ----------------
__global__ __launch_bounds__(256) void scores_kernel(const float* __restrict__ hs,
                                                     const float* __restrict__ rw,
                                                     float* __restrict__ scores) {
    int wave = threadIdx.x >> 6;
    int lane = threadIdx.x & 63;
    int row = blockIdx.x * 4 + wave;           // 0..BT-1
    const float* x = hs + (long)row * DD;
    float s = 0.f;
    for (int i = lane; i < DD; i += 64) s += x[i] * rw[i];
    for (int off = 32; off > 0; off >>= 1) s += __shfl_down(s, off, 64);
    if (lane == 0) scores[row] = s;
}

// ---------------- top-k per batch: bitonic sort ----------------
__global__ __launch_bounds__(1024) void topk_kernel(const float* __restrict__ scores,
                                                    float* __restrict__ flags,
                                                    int* __restrict__ idx_out,
                                                    float* __restrict__ gate_out) {
    int b = blockIdx.x;
    int tid = threadIdx.x;
    __shared__ float sv[TT];
    __shared__ int   si[TT];
    __shared__ int   tmp[KSEL];
    const float* sc = scores + b * TT;
    for (int i = tid; i < TT; i += 1024) { sv[i] = sc[i]; si[i] = i; }
    __syncthreads();
    // descending sort by (score desc, index asc) -- matches lax.top_k tie-break
    for (int k2 = 2; k2 <= TT; k2 <<= 1) {
        for (int j = k2 >> 1; j > 0; j >>= 1) {
            for (int i = tid; i < TT; i += 1024) {
                int ixj = i ^ j;
                if (ixj > i) {
                    float s1 = sv[i], s2 = sv[ixj];
                    int i1 = si[i], i2 = si[ixj];
                    bool before = (s1 > s2) || (s1 == s2 && i1 < i2);
                    bool up = (i & k2) == 0;
                    if (up ? !before : before) {
                        sv[i] = s2; sv[ixj] = s1; si[i] = i2; si[ixj] = i1;
                    }
                }
            }
            __syncthreads();
        }
    }
    for (int i = tid; i < TT; i += 1024) flags[b * TT + i] = 0.f;
    __syncthreads();
    if (tid < KSEL) { tmp[tid] = si[tid]; flags[b * TT + si[tid]] = 1.0f; }
    __syncthreads();
    // ascending sort of the 512 selected indices
    for (int k2 = 2; k2 <= KSEL; k2 <<= 1) {
        for (int j = k2 >> 1; j > 0; j >>= 1) {
            if (tid < KSEL) {
                int i = tid, ixj = tid ^ j;
                if (ixj > i) {
                    int a = tmp[i], c = tmp[ixj];
                    bool up = (i & k2) == 0;
                    if (up ? (a > c) : (a < c)) { tmp[i] = c; tmp[ixj] = a; }
                }
            }
            __syncthreads();
        }
    }
    if (tid < KSEL) {
        int t2 = tmp[tid];
        idx_out[b * KSEL + tid] = t2;
        float s = sc[t2];
        gate_out[b * KSEL + tid] = 1.0f / (1.0f + expf(-s));
    }
}

// ---------------- predictor + both BCE losses (8 tokens / block) ----------------
__device__ __forceinline__ float bce_term(float x, float t) {
    return fmaxf(x, 0.f) - x * t + log1pf(expf(-fabsf(x)));
}

__global__ __launch_bounds__(256) void pred_kernel(const float* __restrict__ hs,
                                                   const float* __restrict__ fc1w,
                                                   const float* __restrict__ fc1b,
                                                   const float* __restrict__ fc2w,
                                                   const float* __restrict__ fc2b,
                                                   const float* __restrict__ scores,
                                                   const float* __restrict__ flags,
                                                   float* __restrict__ acc) {
    __shared__ float xs[8][DD];
    __shared__ float red[256];
    int tid = threadIdx.x;
    long base = (long)blockIdx.x * 8;
    for (int e = tid; e < 8 * DD; e += 256) xs[e >> 10][e & (DD - 1)] = hs[base * DD + e];
    __syncthreads();
    float av[8];
    float bias = fc1b[tid];
#pragma unroll
    for (int t = 0; t < 8; ++t) av[t] = bias;
    for (int d = 0; d < DD; ++d) {
        float w = fc1w[d * 256 + tid];
#pragma unroll
        for (int t = 0; t < 8; ++t) av[t] += xs[t][d] * w;
    }
    float f2 = fc2w[tid];
    float partial[8];
#pragma unroll
    for (int t = 0; t < 8; ++t) {
        float x = av[t];
        float g = 0.5f * x * (1.0f + tanhf(0.7978845608028654f * (x + 0.044715f * x * x * x)));
        partial[t] = g * f2;
    }
    float b2 = fc2b[0];
    for (int t = 0; t < 8; ++t) {
        red[tid] = partial[t];
        __syncthreads();
        for (int s2 = 128; s2 > 0; s2 >>= 1) {
            if (tid < s2) red[tid] += red[tid + s2];
            __syncthreads();
        }
        if (tid == 0) {
            float logit = red[0] + b2;
            long gt = base + t;
            float tgt = flags[gt];
            atomicAdd(acc + 0, bce_term(scores[gt], tgt));
            atomicAdd(acc + 1, bce_term(logit, tgt));
        }
        __syncthreads();
    }
}

// ---------------- rmsnorm (optionally gathering rows via idx) ----------------
__global__ __launch_bounds__(256) void rms_kernel(const float* __restrict__ src,
                                                  const int* __restrict__ idx,
                                                  const float* __restrict__ gamma,
                                                  float* __restrict__ out) {
    int m = blockIdx.x;         // 0..MTOK-1
    int tid = threadIdx.x;
    long srow;
    if (idx) {
        int b = m >> 9;
        srow = ((long)b * TT + idx[m]) * DD;
    } else {
        srow = (long)m * DD;
    }
    __shared__ float red[256];
    float4 v4 = *(const float4*)(src + srow + tid * 4);
    float ss = v4.x * v4.x + v4.y * v4.y + v4.z * v4.z + v4.w * v4.w;
    red[tid] = ss;
    __syncthreads();
    for (int s2 = 128; s2 > 0; s2 >>= 1) {
        if (tid < s2) red[tid] += red[tid + s2];
        __syncthreads();
    }
    float r = rsqrtf(red[0] / (float)DD + 1e-6f);
    float4 g4 = *(const float4*)(gamma + tid * 4);
    float4 o4;
    o4.x = v4.x * r * g4.x; o4.y = v4.y * r * g4.y;
    o4.z = v4.z * r * g4.z; o4.w = v4.w * r * g4.w;
    *(float4*)(out + (long)m * DD + tid * 4) = o4;
}

// ---------------- RoPE on q and k in-place ----------------
__global__ __launch_bounds__(512) void rope_kernel(float* __restrict__ q,
                                                   float* __restrict__ kk,
                                                   const int* __restrict__ idx) {
    int m = blockIdx.x;
    int t = threadIdx.x;
    int h = t >> 5, j = t & 31;
    float pos = (float)idx[m];
    float inv = expf(-((float)(2 * j) / (float)HDD) * 9.210340371976184f); // ln(10000)
    float ang = pos * inv;
    float c = cosf(ang), s = sinf(ang);
    long base = (long)m * DD + h * HDD + j;
    float x1 = q[base], x2 = q[base + 32];
    q[base] = x1 * c - x2 * s;
    q[base + 32] = x2 * c + x1 * s;
    x1 = kk[base]; x2 = kk[base + 32];
    kk[base] = x1 * c - x2 * s;
    kk[base + 32] = x2 * c + x1 * s;
}

// ---------------- flash-style attention, one block per (qtile, b*h) ----------------
__global__ __launch_bounds__(256) void attn_kernel(const float* __restrict__ q,
                                                   const float* __restrict__ kk,
                                                   const float* __restrict__ v,
                                                   float* __restrict__ o) {
    int qt = blockIdx.x;        // 0..7
    int bh = blockIdx.y;        // 0..63
    int b = bh >> 4, h = bh & 15;
    int tid = threadIdx.x;
    int qi = tid >> 2;          // 0..63 (query row in tile)
    int c = tid & 3;            // 0..3  (col group)
    __shared__ float Qs[64][65];
    __shared__ float Ks[64][65];   // reused to hold P after scores are done
    __shared__ float Vs[64][65];
    long qbase = ((long)(b * KSEL + qt * 64) * DD) + h * HDD;
    for (int e = tid; e < 4096; e += 256) {
        int r = e >> 6, d = e & 63;
        Qs[r][d] = q[qbase + (long)r * DD + d];
    }
    float m_run = -1e30f, l_run = 0.f;
    float O[16];
#pragma unroll
    for (int dd = 0; dd < 16; ++dd) O[dd] = 0.f;
    for (int kt = 0; kt <= qt; ++kt) {
        long kbase = ((long)(b * KSEL + kt * 64) * DD) + h * HDD;
        __syncthreads();
        for (int e = tid; e < 4096; e += 256) {
            int r = e >> 6, d = e & 63;
            Ks[r][d] = kk[kbase + (long)r * DD + d];
            Vs[r][d] = v[kbase + (long)r * DD + d];
        }
        __syncthreads();
        float s[16];
#pragma unroll
        for (int j = 0; j < 16; ++j) {
            int kj = c * 16 + j;
            float accd = 0.f;
            for (int d = 0; d < 64; ++d) accd += Qs[qi][d] * Ks[kj][d];
            accd *= 0.125f;
            if (kt == qt && kj > qi) accd = -1e30f;
            s[j] = accd;
        }
        float tm = s[0];
#pragma unroll
        for (int j = 1; j < 16; ++j) tm = fmaxf(tm, s[j]);
        tm = fmaxf(tm, __shfl_xor(tm, 1, 64));
        tm = fmaxf(tm, __shfl_xor(tm, 2, 64));
        float m_new = fmaxf(m_run, tm);
        float alpha = expf(m_run - m_new);
        float psum = 0.f;
#pragma unroll
        for (int j = 0; j < 16; ++j) {
            s[j] = expf(s[j] - m_new);
            psum += s[j];
        }
        psum += __shfl_xor(psum, 1, 64);
        psum += __shfl_xor(psum, 2, 64);
#pragma unroll
        for (int dd = 0; dd < 16; ++dd) O[dd] *= alpha;
        l_run = l_run * alpha + psum;
        m_run = m_new;
        __syncthreads();                 // everyone done reading Ks
#pragma unroll
        for (int j = 0; j < 16; ++j) Ks[qi][c * 16 + j] = s[j];   // P into Ks
        __syncthreads();
        for (int kj = 0; kj < 64; ++kj) {
            float pv = Ks[qi][kj];
#pragma unroll
            for (int dd = 0; dd < 16; ++dd) O[dd] += pv * Vs[kj][c * 16 + dd];
        }
    }
    float inv_l = 1.0f / l_run;
    long obase = ((long)(b * KSEL + qt * 64 + qi) * DD) + h * HDD + c * 16;
#pragma unroll
    for (int dd = 0; dd < 16; ++dd) o[obase + dd] = O[dd] * inv_l;
}

// ---------------- generic tiled f32 GEMM with epilogues ----------------
// EP=0: C = A@B
// EP=1: C = gather(hidden, idx) + A@B            (Wo + residual)
// EP=2: scatter: out[b,row,:] = sel + gate*(hbuf + A@B - sel)
template <int EP>
__global__ __launch_bounds__(256) void gemm_f32(const float* __restrict__ A,
                                                const float* __restrict__ Bm,
                                                float* __restrict__ C,
                                                int M, int N, int K,
                                                const float* __restrict__ hid,
                                                const int* __restrict__ idxp,
                                                const float* __restrict__ gatep,
                                                const float* __restrict__ hbufp,
                                                float* __restrict__ outp) {
    __shared__ __align__(16) float As[16][64];
    __shared__ __align__(16) float Bs[16][64];
    int tid = threadIdx.x;
    int tx = tid & 15, ty = tid >> 4;
    int m0 = blockIdx.y * 64, n0 = blockIdx.x * 64;
    float acc[4][4] = {};
    int arow = tid >> 2;            // 0..63
    int acol = (tid & 3) * 4;       // 0,4,8,12 (k offset)
    int brow = tid >> 4;            // 0..15   (k offset)
    int bcol = (tid & 15) * 4;
    const float* Ap = A + (long)(m0 + arow) * K + acol;
    const float* Bp = Bm + (long)brow * N + n0 + bcol;
    for (int k0 = 0; k0 < K; k0 += 16) {
        float4 avv = *(const float4*)(Ap + k0);
        float4 bvv = *(const float4*)(Bp + (long)k0 * N);
        __syncthreads();
        As[acol + 0][arow] = avv.x;
        As[acol + 1][arow] = avv.y;
        As[acol + 2][arow] = avv.z;
        As[acol + 3][arow] = avv.w;
        *(float4*)&Bs[brow][bcol] = bvv;
        __syncthreads();
#pragma unroll
        for (int kki = 0; kki < 16; ++kki) {
            float4 a4 = *(const float4*)&As[kki][ty * 4];
            float4 b4 = *(const float4*)&Bs[kki][tx * 4];
            float av[4] = {a4.x, a4.y, a4.z, a4.w};
            float bv[4] = {b4.x, b4.y, b4.z, b4.w};
#pragma unroll
            for (int i = 0; i < 4; ++i)
#pragma unroll
                for (int j = 0; j < 4; ++j) acc[i][j] += av[i] * bv[j];
        }
    }
#pragma unroll
    for (int i = 0; i < 4; ++i) {
        int gm = m0 + ty * 4 + i;
#pragma unroll
        for (int j = 0; j < 4; ++j) {
            int gn = n0 + tx * 4 + j;
            if (EP == 0) {
                C[(long)gm * N + gn] = acc[i][j];
            } else if (EP == 1) {
                int b = gm >> 9;
                int row = idxp[gm];
                float selv = hid[((long)b * TT + row) * DD + gn];
                C[(long)gm * N + gn] = selv + acc[i][j];
            } else {
                int b = gm >> 9;
                int row = idxp[gm];
                float gv = gatep[gm];
                float selv = hid[((long)b * TT + row) * DD + gn];
                float u = selv + gv * (hbufp[(long)gm * DD + gn] + acc[i][j] - selv);
                outp[((long)b * TT + row) * DD + gn] = u;
            }
        }
    }
}

// ---------------- fused gate/up SwiGLU GEMM ----------------
__global__ __launch_bounds__(256) void gateup_kernel(const float* __restrict__ A,
                                                     const float* __restrict__ Bg,
                                                     const float* __restrict__ Bu,
                                                     float* __restrict__ act,
                                                     int M, int N, int K) {
    __shared__ __align__(16) float As[16][64];
    __shared__ __align__(16) float Gs[16][64];
    __shared__ __align__(16) float Us[16][64];
    int tid = threadIdx.x;
    int tx = tid & 15, ty = tid >> 4;
    int m0 = blockIdx.y * 64, n0 = blockIdx.x * 64;
    float ag[4][4] = {};
    float au[4][4] = {};
    int arow = tid >> 2;
    int acol = (tid & 3) * 4;
    int brow = tid >> 4;
    int bcol = (tid & 15) * 4;
    const float* Ap = A + (long)(m0 + arow) * K + acol;
    const float* Bgp = Bg + (long)brow * N + n0 + bcol;
    const float* Bup = Bu + (long)brow * N + n0 + bcol;
    for (int k0 = 0; k0 < K; k0 += 16) {
        float4 avv = *(const float4*)(Ap + k0);
        float4 gvv = *(const float4*)(Bgp + (long)k0 * N);
        float4 uvv = *(const float4*)(Bup + (long)k0 * N);
        __syncthreads();
        As[acol + 0][arow] = avv.x;
        As[acol + 1][arow] = avv.y;
        As[acol + 2][arow] = avv.z;
        As[acol + 3][arow] = avv.w;
        *(float4*)&Gs[brow][bcol] = gvv;
        *(float4*)&Us[brow][bcol] = uvv;
        __syncthreads();
#pragma unroll
        for (int kki = 0; kki < 16; ++kki) {
            float4 a4 = *(const float4*)&As[kki][ty * 4];
            float4 g4 = *(const float4*)&Gs[kki][tx * 4];
            float4 u4 = *(const float4*)&Us[kki][tx * 4];
            float av[4] = {a4.x, a4.y, a4.z, a4.w};
            float gv[4] = {g4.x, g4.y, g4.z, g4.w};
            float uv[4] = {u4.x, u4.y, u4.z, u4.w};
#pragma unroll
            for (int i = 0; i < 4; ++i)
#pragma unroll
                for (int j = 0; j < 4; ++j) {
                    ag[i][j] += av[i] * gv[j];
                    au[i][j] += av[i] * uv[j];
                }
        }
    }
#pragma unroll
    for (int i = 0; i < 4; ++i) {
        int gm = m0 + ty * 4 + i;
#pragma unroll
        for (int j = 0; j < 4; ++j) {
            int gn = n0 + tx * 4 + j;
            float g = ag[i][j];
            float silu = g / (1.0f + expf(-g));
            act[(long)gm * N + gn] = silu * au[i][j];
        }
    }
}

// ---------------- finalize aux scalar ----------------
__global__ void finalize_kernel(const float* __restrict__ acc, float* __restrict__ out) {
    out[0] = (acc[0] / (float)BT) * 0.01f + (acc[1] / (float)BT) * 0.01f;
}

extern "C" void kernel_launch(void* const* d_in, const int* in_sizes, int n_in,
                              void* d_out, int out_size, void* d_ws, size_t ws_size,
                              hipStream_t stream) {
    const float* hidden = (const float*)d_in[0];
    const float* router_w = (const float*)d_in[1];
    const float* fc1_w = (const float*)d_in[2];
    const float* fc1_b = (const float*)d_in[3];
    const float* fc2_w = (const float*)d_in[4];
    const float* fc2_b = (const float*)d_in[5];
    const float* ln1_g = (const float*)d_in[6];
    const float* ln2_g = (const float*)d_in[7];
    const float* wq = (const float*)d_in[8];
    const float* wk = (const float*)d_in[9];
    const float* wv = (const float*)d_in[10];
    const float* wo = (const float*)d_in[11];
    const float* w_gate = (const float*)d_in[12];
    const float* w_up = (const float*)d_in[13];
    const float* w_down = (const float*)d_in[14];

    float* out = (float*)d_out;
    char* wsb = (char*)d_ws;

    // workspace layout (bytes)
    float* scores = (float*)(wsb + 0);               // 16384 f
    float* flags = (float*)(wsb + 65536);            // 16384 f
    int* idx = (int*)(wsb + 131072);                 // 2048 i
    float* gate = (float*)(wsb + 139264);            // 2048 f
    float* acc = (float*)(wsb + 147456);             // 2 f
    const size_t BIG = 163840;
    const size_t MB8 = (size_t)MTOK * DD * 4;        // 8 MiB
    float* a_buf = (float*)(wsb + BIG);              // [2048,1024]
    float* q_buf = (float*)(wsb + BIG + MB8);
    float* k_buf = (float*)(wsb + BIG + 2 * MB8);
    float* v_buf = (float*)(wsb + BIG + 3 * MB8);
    float* act_buf = a_buf;                          // [2048,4096] aliases a/q/k/v
    float* att_buf = (float*)(wsb + BIG + 4 * MB8);
    float* h_buf = (float*)(wsb + BIG + 5 * MB8);
    float* m_buf = (float*)(wsb + BIG + 6 * MB8);

    // 1. copy hidden -> out (unselected rows pass through)
    hipMemcpyAsync(d_out, (const void*)hidden, (size_t)BT * DD * 4,
                   hipMemcpyDeviceToDevice, stream);
    // 2. zero loss accumulators
    hipMemsetAsync(acc, 0, 2 * sizeof(float), stream);
    // 3. router scores
    scores_kernel<<<BT / 4, 256, 0, stream>>>(hidden, router_w, scores);
    // 4. top-k, flags, sorted idx, gate
    topk_kernel<<<BB, 1024, 0, stream>>>(scores, flags, idx, gate);
    // 5. predictor + BCE sums
    pred_kernel<<<BT / 8, 256, 0, stream>>>(hidden, fc1_w, fc1_b, fc2_w, fc2_b,
                                            scores, flags, acc);
    // 6. gather + rmsnorm1
    rms_kernel<<<MTOK, 256, 0, stream>>>(hidden, idx, ln1_g, a_buf);
    // 7. q/k/v projections
    dim3 g1(DD / 64, MTOK / 64);
    gemm_f32<0><<<g1, 256, 0, stream>>>(a_buf, wq, q_buf, MTOK, DD, DD,
                                        nullptr, nullptr, nullptr, nullptr, nullptr);
    gemm_f32<0><<<g1, 256, 0, stream>>>(a_buf, wk, k_buf, MTOK, DD, DD,
                                        nullptr, nullptr, nullptr, nullptr, nullptr);
    gemm_f32<0><<<g1, 256, 0, stream>>>(a_buf, wv, v_buf, MTOK, DD, DD,
                                        nullptr, nullptr, nullptr, nullptr, nullptr);
    // 8. RoPE
    rope_kernel<<<MTOK, 512, 0, stream>>>(q_buf, k_buf, idx);
    // 9. attention
    attn_kernel<<<dim3(KSEL / 64, BB * NHH), 256, 0, stream>>>(q_buf, k_buf, v_buf, att_buf);
    // 10. Wo + residual (gathers sel)
    gemm_f32<1><<<g1, 256, 0, stream>>>(att_buf, wo, h_buf, MTOK, DD, DD,
                                        hidden, idx, nullptr, nullptr, nullptr);
    // 11. rmsnorm2
    rms_kernel<<<MTOK, 256, 0, stream>>>(h_buf, nullptr, ln2_g, m_buf);
    // 12. SwiGLU gate/up
    gateup_kernel<<<dim3(FF / 64, MTOK / 64), 256, 0, stream>>>(m_buf, w_gate, w_up,
                                                                act_buf, MTOK, FF, DD);
    // 13. down proj + gated scatter into out
    gemm_f32<2><<<dim3(DD / 64, MTOK / 64), 256, 0, stream>>>(act_buf, w_down, nullptr,
                                                              MTOK, DD, FF,
                                                              hidden, idx, gate, h_buf, out);
    // 14. aux scalar
    finalize_kernel<<<1, 1, 0, stream>>>(acc, out + (size_t)BT * DD);
}

// Round 2
// 853.154 us; speedup vs baseline: 2.4418x; 2.4418x over previous
//
#include <hip/hip_runtime.h>
#include <math.h>

#define BB 4
#define TT 4096
#define DD 1024
#define FF 4096
#define NHH 16
#define HDD 64
#define KSEL 512
#define BT (BB*TT)        // 16384
#define MTOK (BB*KSEL)    // 2048

typedef __bf16 bf16x8 __attribute__((ext_vector_type(8)));
typedef float  f32x4  __attribute__((ext_vector_type(4)));

__device__ __forceinline__ void gl2lds16(const void* g, void* l) {
    __builtin_amdgcn_global_load_lds(
        (const __attribute__((address_space(1))) void*)g,
        (__attribute__((address_space(3))) void*)l,
        16, 0, 0);
}

__device__ __forceinline__ float gelu_tanh(float x) {
    return 0.5f * x * (1.0f + tanhf(0.7978845608028654f * (x + 0.044715f * x * x * x)));
}
__device__ __forceinline__ float bce_term(float x, float t) {
    return fmaxf(x, 0.f) - x * t + log1pf(expf(-fabsf(x)));
}

// ---------------- scores: one wave per row ----------------
__global__ __launch_bounds__(256) void scores_kernel(const float* __restrict__ hs,
                                                     const float* __restrict__ rw,
                                                     float* __restrict__ scores) {
    int wave = threadIdx.x >> 6;
    int lane = threadIdx.x & 63;
    int row = blockIdx.x * 4 + wave;
    const float* x = hs + (long)row * DD;
    float s = 0.f;
    for (int i = lane; i < DD; i += 64) s += x[i] * rw[i];
    for (int off = 32; off > 0; off >>= 1) s += __shfl_down(s, off, 64);
    if (lane == 0) scores[row] = s;
}

// ---------------- top-k per batch: bitonic sort ----------------
__global__ __launch_bounds__(1024) void topk_kernel(const float* __restrict__ scores,
                                                    float* __restrict__ flags,
                                                    int* __restrict__ idx_out,
                                                    float* __restrict__ gate_out) {
    int b = blockIdx.x;
    int tid = threadIdx.x;
    __shared__ float sv[TT];
    __shared__ int   si[TT];
    __shared__ int   tmp[KSEL];
    const float* sc = scores + b * TT;
    for (int i = tid; i < TT; i += 1024) { sv[i] = sc[i]; si[i] = i; }
    __syncthreads();
    for (int k2 = 2; k2 <= TT; k2 <<= 1) {
        for (int j = k2 >> 1; j > 0; j >>= 1) {
            for (int i = tid; i < TT; i += 1024) {
                int ixj = i ^ j;
                if (ixj > i) {
                    float s1 = sv[i], s2 = sv[ixj];
                    int i1 = si[i], i2 = si[ixj];
                    bool before = (s1 > s2) || (s1 == s2 && i1 < i2);
                    bool up = (i & k2) == 0;
                    if (up ? !before : before) {
                        sv[i] = s2; sv[ixj] = s1; si[i] = i2; si[ixj] = i1;
                    }
                }
            }
            __syncthreads();
        }
    }
    for (int i = tid; i < TT; i += 1024) flags[b * TT + i] = 0.f;
    __syncthreads();
    if (tid < KSEL) { tmp[tid] = si[tid]; flags[b * TT + si[tid]] = 1.0f; }
    __syncthreads();
    for (int k2 = 2; k2 <= KSEL; k2 <<= 1) {
        for (int j = k2 >> 1; j > 0; j >>= 1) {
            if (tid < KSEL) {
                int i = tid, ixj = tid ^ j;
                if (ixj > i) {
                    int a = tmp[i], c = tmp[ixj];
                    bool up = (i & k2) == 0;
                    if (up ? (a > c) : (a < c)) { tmp[i] = c; tmp[ixj] = a; }
                }
            }
            __syncthreads();
        }
    }
    if (tid < KSEL) {
        int t2 = tmp[tid];
        idx_out[b * KSEL + tid] = t2;
        float s = sc[t2];
        gate_out[b * KSEL + tid] = 1.0f / (1.0f + expf(-s));
    }
}

// ---------------- cast + transpose: f32 [K][N] -> bf16 [N][K] ----------------
__global__ __launch_bounds__(256) void castT_kernel(const float* __restrict__ in,
                                                    __bf16* __restrict__ out,
                                                    int K, int N) {
    __shared__ float tile[32][33];
    int k0 = blockIdx.y * 32, n0 = blockIdx.x * 32;
    int tx = threadIdx.x & 31, ty = threadIdx.x >> 5;   // 32 x 8
#pragma unroll
    for (int i = 0; i < 32; i += 8)
        tile[ty + i][tx] = in[(long)(k0 + ty + i) * N + n0 + tx];
    __syncthreads();
#pragma unroll
    for (int i = 0; i < 32; i += 8)
        out[(long)(n0 + ty + i) * K + k0 + tx] = (__bf16)tile[tx][ty + i];
}

// ---------------- MFMA GEMM: A[MxK] (bf16 or f32), Bt[NxK] bf16, 128x128 tile ----
// EP 0: Cbf = A@B (bf16 out)
// EP 1: Cbf = gather(hid,idx) + A@B (bf16 out)          [wo + residual]
// EP 2: out[b,row,:] = sel + gate*(h + A@B - sel)       [down + scatter, f32 out]
// EP 3: logits[row] += sum_n gelu(A@B + bias)*w2        [predictor]
template <int EP, bool AF32>
__global__ __launch_bounds__(256) void mfma_gemm(const void* __restrict__ Av,
                                                 const __bf16* __restrict__ Bt,
                                                 int M, int N, int K,
                                                 __bf16* __restrict__ Cbf,
                                                 const float* __restrict__ hid,
                                                 const int* __restrict__ idxp,
                                                 const float* __restrict__ gatep,
                                                 const __bf16* __restrict__ hbf,
                                                 float* __restrict__ outp,
                                                 const float* __restrict__ bias,
                                                 const float* __restrict__ w2,
                                                 float* __restrict__ logits) {
    __shared__ __bf16 As[128 * 32];
    __shared__ __bf16 Bs[128 * 32];
    int tid = threadIdx.x;
    int lane = tid & 63, wave = tid >> 6;
    int wm = wave >> 1, wn = wave & 1;
    int m0 = blockIdx.y * 128, n0 = blockIdx.x * 128;

    f32x4 zv = {0.f, 0.f, 0.f, 0.f};
    f32x4 acc[4][4];
#pragma unroll
    for (int i = 0; i < 4; ++i)
#pragma unroll
        for (int j = 0; j < 4; ++j) acc[i][j] = zv;

    const __bf16* Abf = (const __bf16*)Av;
    const float* Af = (const float*)Av;
    int srow = tid >> 2;
    int scol = (tid & 3) * 8;
    long aoff = (long)(m0 + srow) * K + scol;
    long boff = (long)(n0 + srow) * K + scol;
    __bf16* ldsA = As + wave * 512;
    __bf16* ldsB = Bs + wave * 512;

    for (int k0 = 0; k0 < K; k0 += 32) {
        __syncthreads();
        if (AF32) {
#pragma unroll
            for (int i = 0; i < 4; ++i) {
                int e4 = tid * 4 + i;            // float4 index 0..1023
                int r = e4 >> 3, c4 = e4 & 7;
                float4 v = *(const float4*)(Af + (long)(m0 + r) * K + k0 + c4 * 4);
                __bf16* d = As + r * 32 + c4 * 4;
                d[0] = (__bf16)v.x; d[1] = (__bf16)v.y;
                d[2] = (__bf16)v.z; d[3] = (__bf16)v.w;
            }
        } else {
            gl2lds16(Abf + aoff + k0, ldsA);
            gl2lds16(Abf + aoff + (long)64 * K + k0, ldsA + 2048);
        }
        gl2lds16(Bt + boff + k0, ldsB);
        gl2lds16(Bt + boff + (long)64 * K + k0, ldsB + 2048);
        __syncthreads();

        bf16x8 af[4], bfr[4];
#pragma unroll
        for (int mi = 0; mi < 4; ++mi)
            af[mi] = *(const bf16x8*)(As + (wm * 64 + mi * 16 + (lane & 15)) * 32 + (lane >> 4) * 8);
#pragma unroll
        for (int ni = 0; ni < 4; ++ni)
            bfr[ni] = *(const bf16x8*)(Bs + (wn * 64 + ni * 16 + (lane & 15)) * 32 + (lane >> 4) * 8);
#pragma unroll
        for (int mi = 0; mi < 4; ++mi)
#pragma unroll
            for (int ni = 0; ni < 4; ++ni)
                acc[mi][ni] = __builtin_amdgcn_mfma_f32_16x16x32_bf16(af[mi], bfr[ni], acc[mi][ni], 0, 0, 0);
    }

    int cm = (lane >> 4) * 4;
    int cn = lane & 15;
    if (EP == 3) {
#pragma unroll
        for (int mi = 0; mi < 4; ++mi) {
#pragma unroll
            for (int r = 0; r < 4; ++r) {
                float part = 0.f;
#pragma unroll
                for (int ni = 0; ni < 4; ++ni) {
                    int gn = n0 + wn * 64 + ni * 16 + cn;
                    float x = acc[mi][ni][r] + bias[gn];
                    part += gelu_tanh(x) * w2[gn];
                }
                part += __shfl_xor(part, 1, 64);
                part += __shfl_xor(part, 2, 64);
                part += __shfl_xor(part, 4, 64);
                part += __shfl_xor(part, 8, 64);
                if ((lane & 15) == 0)
                    atomicAdd(&logits[m0 + wm * 64 + mi * 16 + cm + r], part);
            }
        }
        return;
    }
#pragma unroll
    for (int mi = 0; mi < 4; ++mi) {
#pragma unroll
        for (int ni = 0; ni < 4; ++ni) {
#pragma unroll
            for (int r = 0; r < 4; ++r) {
                int gm = m0 + wm * 64 + mi * 16 + cm + r;
                int gn = n0 + wn * 64 + ni * 16 + cn;
                float v = acc[mi][ni][r];
                if (EP == 0) {
                    Cbf[(long)gm * N + gn] = (__bf16)v;
                } else if (EP == 1) {
                    int b = gm >> 9;
                    int row = idxp[gm];
                    float selv = hid[((long)b * TT + row) * DD + gn];
                    Cbf[(long)gm * N + gn] = (__bf16)(selv + v);
                } else if (EP == 2) {
                    int b = gm >> 9;
                    int row = idxp[gm];
                    float selv = hid[((long)b * TT + row) * DD + gn];
                    float hv = (float)hbf[(long)gm * DD + gn];
                    outp[((long)b * TT + row) * DD + gn] = selv + gatep[gm] * (hv + v - selv);
                }
            }
        }
    }
}

// ---------------- fused gate/up SwiGLU MFMA GEMM ----------------
__global__ __launch_bounds__(256) void gateup_mfma(const __bf16* __restrict__ A,
                                                   const __bf16* __restrict__ Bg,
                                                   const __bf16* __restrict__ Bu,
                                                   __bf16* __restrict__ act,
                                                   int M, int N, int K) {
    __shared__ __bf16 As[128 * 32];
    __shared__ __bf16 Gs[128 * 32];
    __shared__ __bf16 Us[128 * 32];
    int tid = threadIdx.x;
    int lane = tid & 63, wave = tid >> 6;
    int wm = wave >> 1, wn = wave & 1;
    int m0 = blockIdx.y * 128, n0 = blockIdx.x * 128;

    f32x4 zv = {0.f, 0.f, 0.f, 0.f};
    f32x4 ag[4][4], au[4][4];
#pragma unroll
    for (int i = 0; i < 4; ++i)
#pragma unroll
        for (int j = 0; j < 4; ++j) { ag[i][j] = zv; au[i][j] = zv; }

    int srow = tid >> 2;
    int scol = (tid & 3) * 8;
    long aoff = (long)(m0 + srow) * K + scol;
    long boff = (long)(n0 + srow) * K + scol;
    __bf16* ldsA = As + wave * 512;
    __bf16* ldsG = Gs + wave * 512;
    __bf16* ldsU = Us + wave * 512;

    for (int k0 = 0; k0 < K; k0 += 32) {
        __syncthreads();
        gl2lds16(A + aoff + k0, ldsA);
        gl2lds16(A + aoff + (long)64 * K + k0, ldsA + 2048);
        gl2lds16(Bg + boff + k0, ldsG);
        gl2lds16(Bg + boff + (long)64 * K + k0, ldsG + 2048);
        gl2lds16(Bu + boff + k0, ldsU);
        gl2lds16(Bu + boff + (long)64 * K + k0, ldsU + 2048);
        __syncthreads();

        bf16x8 af[4], gf[4], uf[4];
#pragma unroll
        for (int mi = 0; mi < 4; ++mi)
            af[mi] = *(const bf16x8*)(As + (wm * 64 + mi * 16 + (lane & 15)) * 32 + (lane >> 4) * 8);
#pragma unroll
        for (int ni = 0; ni < 4; ++ni) {
            gf[ni] = *(const bf16x8*)(Gs + (wn * 64 + ni * 16 + (lane & 15)) * 32 + (lane >> 4) * 8);
            uf[ni] = *(const bf16x8*)(Us + (wn * 64 + ni * 16 + (lane & 15)) * 32 + (lane >> 4) * 8);
        }
#pragma unroll
        for (int mi = 0; mi < 4; ++mi)
#pragma unroll
            for (int ni = 0; ni < 4; ++ni) {
                ag[mi][ni] = __builtin_amdgcn_mfma_f32_16x16x32_bf16(af[mi], gf[ni], ag[mi][ni], 0, 0, 0);
                au[mi][ni] = __builtin_amdgcn_mfma_f32_16x16x32_bf16(af[mi], uf[ni], au[mi][ni], 0, 0, 0);
            }
    }

    int cm = (lane >> 4) * 4;
    int cn = lane & 15;
#pragma unroll
    for (int mi = 0; mi < 4; ++mi)
#pragma unroll
        for (int ni = 0; ni < 4; ++ni)
#pragma unroll
            for (int r = 0; r < 4; ++r) {
                int gm = m0 + wm * 64 + mi * 16 + cm + r;
                int gn = n0 + wn * 64 + ni * 16 + cn;
                float g = ag[mi][ni][r];
                float silu = g / (1.0f + expf(-g));
                act[(long)gm * N + gn] = (__bf16)(silu * au[mi][ni][r]);
            }
}

// ---------------- rmsnorm: f32-gather or bf16 input, bf16 out ----------------
template <typename TIN>
__global__ __launch_bounds__(256) void rms_kernel(const TIN* __restrict__ src,
                                                  const int* __restrict__ idx,
                                                  const float* __restrict__ gamma,
                                                  __bf16* __restrict__ out) {
    int m = blockIdx.x;
    int tid = threadIdx.x;
    long srow;
    if (idx) {
        int b = m >> 9;
        srow = ((long)b * TT + idx[m]) * DD;
    } else {
        srow = (long)m * DD;
    }
    __shared__ float red[256];
    float v[4];
#pragma unroll
    for (int i = 0; i < 4; ++i) v[i] = (float)src[srow + tid * 4 + i];
    float ss = v[0] * v[0] + v[1] * v[1] + v[2] * v[2] + v[3] * v[3];
    red[tid] = ss;
    __syncthreads();
    for (int s2 = 128; s2 > 0; s2 >>= 1) {
        if (tid < s2) red[tid] += red[tid + s2];
        __syncthreads();
    }
    float r = rsqrtf(red[0] / (float)DD + 1e-6f);
    float4 g4 = *(const float4*)(gamma + tid * 4);
    long obase = (long)m * DD + tid * 4;
    out[obase + 0] = (__bf16)(v[0] * r * g4.x);
    out[obase + 1] = (__bf16)(v[1] * r * g4.y);
    out[obase + 2] = (__bf16)(v[2] * r * g4.z);
    out[obase + 3] = (__bf16)(v[3] * r * g4.w);
}

// ---------------- RoPE on fused qkv (bf16, [M][3072]) ----------------
__global__ __launch_bounds__(512) void rope_kernel(__bf16* __restrict__ qkv,
                                                   const int* __restrict__ idx) {
    int m = blockIdx.x;
    int t = threadIdx.x;
    int h = t >> 5, j = t & 31;
    float pos = (float)idx[m];
    float inv = expf(-((float)(2 * j) / (float)HDD) * 9.210340371976184f);
    float ang = pos * inv;
    float c = cosf(ang), s = sinf(ang);
    long base = (long)m * 3072 + h * HDD + j;
    float x1 = (float)qkv[base], x2 = (float)qkv[base + 32];
    qkv[base] = (__bf16)(x1 * c - x2 * s);
    qkv[base + 32] = (__bf16)(x2 * c + x1 * s);
    long kbase = base + 1024;
    x1 = (float)qkv[kbase]; x2 = (float)qkv[kbase + 32];
    qkv[kbase] = (__bf16)(x1 * c - x2 * s);
    qkv[kbase + 32] = (__bf16)(x2 * c + x1 * s);
}

// ---------------- flash-style attention (bf16 in, bf16 out) ----------------
__global__ __launch_bounds__(256) void attn_kernel(const __bf16* __restrict__ qkv,
                                                   __bf16* __restrict__ o) {
    int qt = blockIdx.x;
    int bh = blockIdx.y;
    int b = bh >> 4, h = bh & 15;
    int tid = threadIdx.x;
    int qi = tid >> 2;
    int c = tid & 3;
    __shared__ float Qs[64][65];
    __shared__ float Ks[64][65];
    __shared__ float Vs[64][65];
    long qbase = ((long)(b * KSEL + qt * 64) * 3072) + h * HDD;
    for (int e = tid; e < 4096; e += 256) {
        int r = e >> 6, d = e & 63;
        Qs[r][d] = (float)qkv[qbase + (long)r * 3072 + d];
    }
    float m_run = -1e30f, l_run = 0.f;
    float O[16];
#pragma unroll
    for (int dd = 0; dd < 16; ++dd) O[dd] = 0.f;
    for (int kt = 0; kt <= qt; ++kt) {
        long kbase = ((long)(b * KSEL + kt * 64) * 3072) + h * HDD + 1024;
        __syncthreads();
        for (int e = tid; e < 4096; e += 256) {
            int r = e >> 6, d = e & 63;
            Ks[r][d] = (float)qkv[kbase + (long)r * 3072 + d];
            Vs[r][d] = (float)qkv[kbase + (long)r * 3072 + d + 1024];
        }
        __syncthreads();
        float s[16];
#pragma unroll
        for (int j = 0; j < 16; ++j) {
            int kj = c * 16 + j;
            float accd = 0.f;
            for (int d = 0; d < 64; ++d) accd += Qs[qi][d] * Ks[kj][d];
            accd *= 0.125f;
            if (kt == qt && kj > qi) accd = -1e30f;
            s[j] = accd;
        }
        float tm = s[0];
#pragma unroll
        for (int j = 1; j < 16; ++j) tm = fmaxf(tm, s[j]);
        tm = fmaxf(tm, __shfl_xor(tm, 1, 64));
        tm = fmaxf(tm, __shfl_xor(tm, 2, 64));
        float m_new = fmaxf(m_run, tm);
        float alpha = expf(m_run - m_new);
        float psum = 0.f;
#pragma unroll
        for (int j = 0; j < 16; ++j) {
            s[j] = expf(s[j] - m_new);
            psum += s[j];
        }
        psum += __shfl_xor(psum, 1, 64);
        psum += __shfl_xor(psum, 2, 64);
#pragma unroll
        for (int dd = 0; dd < 16; ++dd) O[dd] *= alpha;
        l_run = l_run * alpha + psum;
        m_run = m_new;
        __syncthreads();
#pragma unroll
        for (int j = 0; j < 16; ++j) Ks[qi][c * 16 + j] = s[j];
        __syncthreads();
        for (int kj = 0; kj < 64; ++kj) {
            float pv = Ks[qi][kj];
#pragma unroll
            for (int dd = 0; dd < 16; ++dd) O[dd] += pv * Vs[kj][c * 16 + dd];
        }
    }
    float inv_l = 1.0f / l_run;
    long obase = ((long)(b * KSEL + qt * 64 + qi) * DD) + h * HDD + c * 16;
#pragma unroll
    for (int dd = 0; dd < 16; ++dd) o[obase + dd] = (__bf16)(O[dd] * inv_l);
}

// ---------------- BCE losses ----------------
__global__ __launch_bounds__(256) void bce_kernel(const float* __restrict__ scores,
                                                  const float* __restrict__ logits,
                                                  const float* __restrict__ flags,
                                                  const float* __restrict__ fc2b,
                                                  float* __restrict__ acc) {
    int i = blockIdx.x * 256 + threadIdx.x;
    int tid = threadIdx.x;
    __shared__ float r0[256];
    __shared__ float r1[256];
    float tgt = flags[i];
    r0[tid] = bce_term(scores[i], tgt);
    r1[tid] = bce_term(logits[i] + fc2b[0], tgt);
    __syncthreads();
    for (int s2 = 128; s2 > 0; s2 >>= 1) {
        if (tid < s2) { r0[tid] += r0[tid + s2]; r1[tid] += r1[tid + s2]; }
        __syncthreads();
    }
    if (tid == 0) {
        atomicAdd(acc + 0, r0[0]);
        atomicAdd(acc + 1, r1[0]);
    }
}

__global__ void finalize_kernel(const float* __restrict__ acc, float* __restrict__ out) {
    out[0] = (acc[0] / (float)BT) * 0.01f + (acc[1] / (float)BT) * 0.01f;
}

extern "C" void kernel_launch(void* const* d_in, const int* in_sizes, int n_in,
                              void* d_out, int out_size, void* d_ws, size_t ws_size,
                              hipStream_t stream) {
    const float* hidden = (const float*)d_in[0];
    const float* router_w = (const float*)d_in[1];
    const float* fc1_w = (const float*)d_in[2];
    const float* fc1_b = (const float*)d_in[3];
    const float* fc2_w = (const float*)d_in[4];
    const float* fc2_b = (const float*)d_in[5];
    const float* ln1_g = (const float*)d_in[6];
    const float* ln2_g = (const float*)d_in[7];
    const float* wq = (const float*)d_in[8];
    const float* wk = (const float*)d_in[9];
    const float* wv = (const float*)d_in[10];
    const float* wo = (const float*)d_in[11];
    const float* w_gate = (const float*)d_in[12];
    const float* w_up = (const float*)d_in[13];
    const float* w_down = (const float*)d_in[14];

    float* out = (float*)d_out;
    char* wsb = (char*)d_ws;

    // ---- workspace layout (54.75 MiB total; 56.16 MiB proven available) ----
    float* scores = (float*)(wsb + 0x0);          // 64 KB
    float* flags  = (float*)(wsb + 0x10000);      // 64 KB
    float* logits = (float*)(wsb + 0x20000);      // 64 KB
    int*   idx    = (int*)  (wsb + 0x30000);      // 8 KB
    float* gate   = (float*)(wsb + 0x32000);      // 8 KB
    float* acc    = (float*)(wsb + 0x34000);      // pad to 0x40000
    __bf16* fc1_t = (__bf16*)(wsb + 0x40000);     // [256][1024]   512 KB
    __bf16* wo_t  = (__bf16*)(wsb + 0xC0000);     // [1024][1024]  2 MB
    __bf16* w1    = (__bf16*)(wsb + 0x2C0000);    // 8 MB: wqkv_t [3072][1024] -> wd_t [1024][4096]
    __bf16* wg_t  = (__bf16*)(wsb + 0xAC0000);    // [4096][1024]  8 MB
    __bf16* wu_t  = (__bf16*)(wsb + 0x12C0000);   // [4096][1024]  8 MB
    __bf16* a_bf  = (__bf16*)(wsb + 0x1AC0000);   // [2048][1024]  4 MB
    __bf16* qkv   = (__bf16*)(wsb + 0x1EC0000);   // [2048][3072] 12 MB
    __bf16* act_bf= (__bf16*)(wsb + 0x1AC0000);   // [2048][4096] 16 MB (aliases a_bf+qkv)
    __bf16* att_bf= (__bf16*)(wsb + 0x2AC0000);   // [2048][1024]  4 MB
    __bf16* h_bf  = (__bf16*)(wsb + 0x2EC0000);   // [2048][1024]  4 MB
    __bf16* m_bf  = (__bf16*)(wsb + 0x32C0000);   // [2048][1024]  4 MB

    __bf16* wqkv_t = w1;
    __bf16* wd_t   = w1;

    // 1. passthrough copy + zero accumulators
    hipMemcpyAsync(d_out, (const void*)hidden, (size_t)BT * DD * 4,
                   hipMemcpyDeviceToDevice, stream);
    hipMemsetAsync(acc, 0, 2 * sizeof(float), stream);
    hipMemsetAsync(logits, 0, BT * sizeof(float), stream);

    // 2. router scores + top-k
    scores_kernel<<<BT / 4, 256, 0, stream>>>(hidden, router_w, scores);
    topk_kernel<<<BB, 1024, 0, stream>>>(scores, flags, idx, gate);

    // 3. predictor: fc1 GEMM (f32 A staged->bf16) with fused gelu*w2 row-reduce
    castT_kernel<<<dim3(256 / 32, DD / 32), 256, 0, stream>>>(fc1_w, fc1_t, DD, 256);
    mfma_gemm<3, true><<<dim3(256 / 128, BT / 128), 256, 0, stream>>>(
        hidden, fc1_t, BT, 256, DD, nullptr, nullptr, nullptr, nullptr, nullptr,
        nullptr, fc1_b, fc2_w, logits);
    bce_kernel<<<BT / 256, 256, 0, stream>>>(scores, logits, flags, fc2_b, acc);

    // 4. gather + rmsnorm1 -> a_bf
    rms_kernel<float><<<MTOK, 256, 0, stream>>>(hidden, idx, ln1_g, a_bf);

    // 5. fused qkv projection
    castT_kernel<<<dim3(DD / 32, DD / 32), 256, 0, stream>>>(wq, wqkv_t, DD, DD);
    castT_kernel<<<dim3(DD / 32, DD / 32), 256, 0, stream>>>(wk, wqkv_t + (size_t)1024 * 1024, DD, DD);
    castT_kernel<<<dim3(DD / 32, DD / 32), 256, 0, stream>>>(wv, wqkv_t + (size_t)2048 * 1024, DD, DD);
    mfma_gemm<0, false><<<dim3(3072 / 128, MTOK / 128), 256, 0, stream>>>(
        a_bf, wqkv_t, MTOK, 3072, DD, qkv, nullptr, nullptr, nullptr, nullptr,
        nullptr, nullptr, nullptr, nullptr);

    // 6. RoPE + attention
    rope_kernel<<<MTOK, 512, 0, stream>>>(qkv, idx);
    attn_kernel<<<dim3(KSEL / 64, BB * NHH), 256, 0, stream>>>(qkv, att_bf);

    // 7. Wo + residual -> h_bf
    castT_kernel<<<dim3(DD / 32, DD / 32), 256, 0, stream>>>(wo, wo_t, DD, DD);
    mfma_gemm<1, false><<<dim3(DD / 128, MTOK / 128), 256, 0, stream>>>(
        att_bf, wo_t, MTOK, DD, DD, h_bf, hidden, idx, nullptr, nullptr,
        nullptr, nullptr, nullptr, nullptr);

    // 8. rmsnorm2 -> m_bf
    rms_kernel<__bf16><<<MTOK, 256, 0, stream>>>(h_bf, nullptr, ln2_g, m_bf);

    // 9. fused SwiGLU gate/up -> act_bf
    castT_kernel<<<dim3(FF / 32, DD / 32), 256, 0, stream>>>(w_gate, wg_t, DD, FF);
    castT_kernel<<<dim3(FF / 32, DD / 32), 256, 0, stream>>>(w_up, wu_t, DD, FF);
    gateup_mfma<<<dim3(FF / 128, MTOK / 128), 256, 0, stream>>>(m_bf, wg_t, wu_t,
                                                                act_bf, MTOK, FF, DD);

    // 10. down proj + gated scatter into out (wd_t reuses wqkv_t region)
    castT_kernel<<<dim3(DD / 32, FF / 32), 256, 0, stream>>>(w_down, wd_t, FF, DD);
    mfma_gemm<2, false><<<dim3(DD / 128, MTOK / 128), 256, 0, stream>>>(
        act_bf, wd_t, MTOK, DD, FF, nullptr, hidden, idx, gate, h_bf, out,
        nullptr, nullptr, nullptr);

    // 11. aux scalar
    finalize_kernel<<<1, 1, 0, stream>>>(acc, out + (size_t)BT * DD);
}

// Round 3
// 609.919 us; speedup vs baseline: 3.4155x; 1.3988x over previous
//
#include <hip/hip_runtime.h>
#include <math.h>

#define BB 4
#define TT 4096
#define DD 1024
#define FF 4096
#define NHH 16
#define HDD 64
#define KSEL 512
#define BT (BB*TT)        // 16384
#define MTOK (BB*KSEL)    // 2048
#define APAD 72           // 64 + 8 pad (keeps 16B align, breaks pow2 stride)

typedef __bf16 bf16x8 __attribute__((ext_vector_type(8)));
typedef __bf16 bf16x4 __attribute__((ext_vector_type(4)));
typedef float  f32x4  __attribute__((ext_vector_type(4)));

__device__ __forceinline__ void gl2lds16(const void* g, void* l) {
    __builtin_amdgcn_global_load_lds(
        (const __attribute__((address_space(1))) void*)g,
        (__attribute__((address_space(3))) void*)l,
        16, 0, 0);
}

__device__ __forceinline__ float gelu_tanh(float x) {
    return 0.5f * x * (1.0f + tanhf(0.7978845608028654f * (x + 0.044715f * x * x * x)));
}
__device__ __forceinline__ float bce_term(float x, float t) {
    return fmaxf(x, 0.f) - x * t + log1pf(expf(-fabsf(x)));
}

// ---------------- fused: passthrough copy + bf16 cast + router scores ----------------
__global__ __launch_bounds__(256) void fused_pass(const float* __restrict__ hs,
                                                  const float* __restrict__ rw,
                                                  float* __restrict__ outp,
                                                  __bf16* __restrict__ hbf,
                                                  float* __restrict__ scores) {
    int wave = threadIdx.x >> 6, lane = threadIdx.x & 63;
    int row = blockIdx.x * 4 + wave;
    long base = (long)row * DD;
    float s = 0.f;
#pragma unroll
    for (int it = 0; it < 4; ++it) {
        int c = it * 256 + lane * 4;
        float4 v = *(const float4*)(hs + base + c);
        *(float4*)(outp + base + c) = v;
        float4 r4 = *(const float4*)(rw + c);
        s += v.x * r4.x + v.y * r4.y + v.z * r4.z + v.w * r4.w;
        bf16x4 b4 = {(__bf16)v.x, (__bf16)v.y, (__bf16)v.z, (__bf16)v.w};
        *(bf16x4*)(hbf + base + c) = b4;
    }
    for (int off = 32; off > 0; off >>= 1) s += __shfl_down(s, off, 64);
    if (lane == 0) scores[row] = s;
}

// ---------------- top-k per batch: bitonic sort ----------------
__global__ __launch_bounds__(1024) void topk_kernel(const float* __restrict__ scores,
                                                    float* __restrict__ flags,
                                                    int* __restrict__ idx_out,
                                                    float* __restrict__ gate_out) {
    int b = blockIdx.x;
    int tid = threadIdx.x;
    __shared__ float sv[TT];
    __shared__ int   si[TT];
    __shared__ int   tmp[KSEL];
    const float* sc = scores + b * TT;
    for (int i = tid; i < TT; i += 1024) { sv[i] = sc[i]; si[i] = i; }
    __syncthreads();
    for (int k2 = 2; k2 <= TT; k2 <<= 1) {
        for (int j = k2 >> 1; j > 0; j >>= 1) {
            for (int i = tid; i < TT; i += 1024) {
                int ixj = i ^ j;
                if (ixj > i) {
                    float s1 = sv[i], s2 = sv[ixj];
                    int i1 = si[i], i2 = si[ixj];
                    bool before = (s1 > s2) || (s1 == s2 && i1 < i2);
                    bool up = (i & k2) == 0;
                    if (up ? !before : before) {
                        sv[i] = s2; sv[ixj] = s1; si[i] = i2; si[ixj] = i1;
                    }
                }
            }
            __syncthreads();
        }
    }
    for (int i = tid; i < TT; i += 1024) flags[b * TT + i] = 0.f;
    __syncthreads();
    if (tid < KSEL) { tmp[tid] = si[tid]; flags[b * TT + si[tid]] = 1.0f; }
    __syncthreads();
    for (int k2 = 2; k2 <= KSEL; k2 <<= 1) {
        for (int j = k2 >> 1; j > 0; j >>= 1) {
            if (tid < KSEL) {
                int i = tid, ixj = tid ^ j;
                if (ixj > i) {
                    int a = tmp[i], c = tmp[ixj];
                    bool up = (i & k2) == 0;
                    if (up ? (a > c) : (a < c)) { tmp[i] = c; tmp[ixj] = a; }
                }
            }
            __syncthreads();
        }
    }
    if (tid < KSEL) {
        int t2 = tmp[tid];
        idx_out[b * KSEL + tid] = t2;
        float s = sc[t2];
        gate_out[b * KSEL + tid] = 1.0f / (1.0f + expf(-s));
    }
}

// ---------------- cast + transpose: f32 [K][N] -> bf16 [N][K] ----------------
__global__ __launch_bounds__(256) void castT_kernel(const float* __restrict__ in,
                                                    __bf16* __restrict__ out,
                                                    int K, int N) {
    __shared__ float tile[32][33];
    int k0 = blockIdx.y * 32, n0 = blockIdx.x * 32;
    int tx = threadIdx.x & 31, ty = threadIdx.x >> 5;
#pragma unroll
    for (int i = 0; i < 32; i += 8)
        tile[ty + i][tx] = in[(long)(k0 + ty + i) * N + n0 + tx];
    __syncthreads();
#pragma unroll
    for (int i = 0; i < 32; i += 8)
        out[(long)(n0 + ty + i) * K + k0 + tx] = (__bf16)tile[tx][ty + i];
}

// ---------------- MFMA GEMM: A[MxK] bf16, Bt[NxK] bf16, 128x128 tile ----------------
// EP 0: Cbf = A@B (bf16 out)
// EP 1: Cbf = gather(hid,idx) + A@B (bf16 out)          [wo + residual]
// EP 2: out[b,row,:] = sel + gate*(h + A@B - sel)       [down + scatter, f32 out]
// EP 3: logits[row] += sum_n gelu(A@B + bias)*w2        [predictor]
template <int EP>
__global__ __launch_bounds__(256) void mfma_gemm(const __bf16* __restrict__ Abf,
                                                 const __bf16* __restrict__ Bt,
                                                 int M, int N, int K,
                                                 __bf16* __restrict__ Cbf,
                                                 const float* __restrict__ hid,
                                                 const int* __restrict__ idxp,
                                                 const float* __restrict__ gatep,
                                                 const __bf16* __restrict__ hbf,
                                                 float* __restrict__ outp,
                                                 const float* __restrict__ bias,
                                                 const float* __restrict__ w2,
                                                 float* __restrict__ logits) {
    __shared__ __bf16 As[128 * 32];
    __shared__ __bf16 Bs[128 * 32];
    int tid = threadIdx.x;
    int lane = tid & 63, wave = tid >> 6;
    int wm = wave >> 1, wn = wave & 1;
    int m0 = blockIdx.y * 128, n0 = blockIdx.x * 128;

    f32x4 zv = {0.f, 0.f, 0.f, 0.f};
    f32x4 acc[4][4];
#pragma unroll
    for (int i = 0; i < 4; ++i)
#pragma unroll
        for (int j = 0; j < 4; ++j) acc[i][j] = zv;

    int srow = tid >> 2;
    int scol = (tid & 3) * 8;
    long aoff = (long)(m0 + srow) * K + scol;
    long boff = (long)(n0 + srow) * K + scol;
    __bf16* ldsA = As + wave * 512;
    __bf16* ldsB = Bs + wave * 512;

    for (int k0 = 0; k0 < K; k0 += 32) {
        __syncthreads();
        gl2lds16(Abf + aoff + k0, ldsA);
        gl2lds16(Abf + aoff + (long)64 * K + k0, ldsA + 2048);
        gl2lds16(Bt + boff + k0, ldsB);
        gl2lds16(Bt + boff + (long)64 * K + k0, ldsB + 2048);
        __syncthreads();

        bf16x8 af[4], bfr[4];
#pragma unroll
        for (int mi = 0; mi < 4; ++mi)
            af[mi] = *(const bf16x8*)(As + (wm * 64 + mi * 16 + (lane & 15)) * 32 + (lane >> 4) * 8);
#pragma unroll
        for (int ni = 0; ni < 4; ++ni)
            bfr[ni] = *(const bf16x8*)(Bs + (wn * 64 + ni * 16 + (lane & 15)) * 32 + (lane >> 4) * 8);
#pragma unroll
        for (int mi = 0; mi < 4; ++mi)
#pragma unroll
            for (int ni = 0; ni < 4; ++ni)
                acc[mi][ni] = __builtin_amdgcn_mfma_f32_16x16x32_bf16(af[mi], bfr[ni], acc[mi][ni], 0, 0, 0);
    }

    int cm = (lane >> 4) * 4;
    int cn = lane & 15;
    if (EP == 3) {
#pragma unroll
        for (int mi = 0; mi < 4; ++mi) {
#pragma unroll
            for (int r = 0; r < 4; ++r) {
                float part = 0.f;
#pragma unroll
                for (int ni = 0; ni < 4; ++ni) {
                    int gn = n0 + wn * 64 + ni * 16 + cn;
                    float x = acc[mi][ni][r] + bias[gn];
                    part += gelu_tanh(x) * w2[gn];
                }
                part += __shfl_xor(part, 1, 64);
                part += __shfl_xor(part, 2, 64);
                part += __shfl_xor(part, 4, 64);
                part += __shfl_xor(part, 8, 64);
                if ((lane & 15) == 0)
                    atomicAdd(&logits[m0 + wm * 64 + mi * 16 + cm + r], part);
            }
        }
        return;
    }
#pragma unroll
    for (int mi = 0; mi < 4; ++mi) {
#pragma unroll
        for (int ni = 0; ni < 4; ++ni) {
#pragma unroll
            for (int r = 0; r < 4; ++r) {
                int gm = m0 + wm * 64 + mi * 16 + cm + r;
                int gn = n0 + wn * 64 + ni * 16 + cn;
                float v = acc[mi][ni][r];
                if (EP == 0) {
                    Cbf[(long)gm * N + gn] = (__bf16)v;
                } else if (EP == 1) {
                    int b = gm >> 9;
                    int row = idxp[gm];
                    float selv = hid[((long)b * TT + row) * DD + gn];
                    Cbf[(long)gm * N + gn] = (__bf16)(selv + v);
                } else if (EP == 2) {
                    int b = gm >> 9;
                    int row = idxp[gm];
                    float selv = hid[((long)b * TT + row) * DD + gn];
                    float hv = (float)hbf[(long)gm * DD + gn];
                    outp[((long)b * TT + row) * DD + gn] = selv + gatep[gm] * (hv + v - selv);
                }
            }
        }
    }
}

// ---------------- fused gate/up SwiGLU MFMA GEMM ----------------
__global__ __launch_bounds__(256) void gateup_mfma(const __bf16* __restrict__ A,
                                                   const __bf16* __restrict__ Bg,
                                                   const __bf16* __restrict__ Bu,
                                                   __bf16* __restrict__ act,
                                                   int M, int N, int K) {
    __shared__ __bf16 As[128 * 32];
    __shared__ __bf16 Gs[128 * 32];
    __shared__ __bf16 Us[128 * 32];
    int tid = threadIdx.x;
    int lane = tid & 63, wave = tid >> 6;
    int wm = wave >> 1, wn = wave & 1;
    int m0 = blockIdx.y * 128, n0 = blockIdx.x * 128;

    f32x4 zv = {0.f, 0.f, 0.f, 0.f};
    f32x4 ag[4][4], au[4][4];
#pragma unroll
    for (int i = 0; i < 4; ++i)
#pragma unroll
        for (int j = 0; j < 4; ++j) { ag[i][j] = zv; au[i][j] = zv; }

    int srow = tid >> 2;
    int scol = (tid & 3) * 8;
    long aoff = (long)(m0 + srow) * K + scol;
    long boff = (long)(n0 + srow) * K + scol;
    __bf16* ldsA = As + wave * 512;
    __bf16* ldsG = Gs + wave * 512;
    __bf16* ldsU = Us + wave * 512;

    for (int k0 = 0; k0 < K; k0 += 32) {
        __syncthreads();
        gl2lds16(A + aoff + k0, ldsA);
        gl2lds16(A + aoff + (long)64 * K + k0, ldsA + 2048);
        gl2lds16(Bg + boff + k0, ldsG);
        gl2lds16(Bg + boff + (long)64 * K + k0, ldsG + 2048);
        gl2lds16(Bu + boff + k0, ldsU);
        gl2lds16(Bu + boff + (long)64 * K + k0, ldsU + 2048);
        __syncthreads();

        bf16x8 af[4], gf[4], uf[4];
#pragma unroll
        for (int mi = 0; mi < 4; ++mi)
            af[mi] = *(const bf16x8*)(As + (wm * 64 + mi * 16 + (lane & 15)) * 32 + (lane >> 4) * 8);
#pragma unroll
        for (int ni = 0; ni < 4; ++ni) {
            gf[ni] = *(const bf16x8*)(Gs + (wn * 64 + ni * 16 + (lane & 15)) * 32 + (lane >> 4) * 8);
            uf[ni] = *(const bf16x8*)(Us + (wn * 64 + ni * 16 + (lane & 15)) * 32 + (lane >> 4) * 8);
        }
#pragma unroll
        for (int mi = 0; mi < 4; ++mi)
#pragma unroll
            for (int ni = 0; ni < 4; ++ni) {
                ag[mi][ni] = __builtin_amdgcn_mfma_f32_16x16x32_bf16(af[mi], gf[ni], ag[mi][ni], 0, 0, 0);
                au[mi][ni] = __builtin_amdgcn_mfma_f32_16x16x32_bf16(af[mi], uf[ni], au[mi][ni], 0, 0, 0);
            }
    }

    int cm = (lane >> 4) * 4;
    int cn = lane & 15;
#pragma unroll
    for (int mi = 0; mi < 4; ++mi)
#pragma unroll
        for (int ni = 0; ni < 4; ++ni)
#pragma unroll
            for (int r = 0; r < 4; ++r) {
                int gm = m0 + wm * 64 + mi * 16 + cm + r;
                int gn = n0 + wn * 64 + ni * 16 + cn;
                float g = ag[mi][ni][r];
                float silu = g / (1.0f + expf(-g));
                act[(long)gm * N + gn] = (__bf16)(silu * au[mi][ni][r]);
            }
}

// ---------------- rmsnorm: f32-gather or bf16 input, bf16 out ----------------
template <typename TIN>
__global__ __launch_bounds__(256) void rms_kernel(const TIN* __restrict__ src,
                                                  const int* __restrict__ idx,
                                                  const float* __restrict__ gamma,
                                                  __bf16* __restrict__ out) {
    int m = blockIdx.x;
    int tid = threadIdx.x;
    long srow;
    if (idx) {
        int b = m >> 9;
        srow = ((long)b * TT + idx[m]) * DD;
    } else {
        srow = (long)m * DD;
    }
    __shared__ float red[256];
    float v[4];
#pragma unroll
    for (int i = 0; i < 4; ++i) v[i] = (float)src[srow + tid * 4 + i];
    float ss = v[0] * v[0] + v[1] * v[1] + v[2] * v[2] + v[3] * v[3];
    red[tid] = ss;
    __syncthreads();
    for (int s2 = 128; s2 > 0; s2 >>= 1) {
        if (tid < s2) red[tid] += red[tid + s2];
        __syncthreads();
    }
    float r = rsqrtf(red[0] / (float)DD + 1e-6f);
    float4 g4 = *(const float4*)(gamma + tid * 4);
    long obase = (long)m * DD + tid * 4;
    out[obase + 0] = (__bf16)(v[0] * r * g4.x);
    out[obase + 1] = (__bf16)(v[1] * r * g4.y);
    out[obase + 2] = (__bf16)(v[2] * r * g4.z);
    out[obase + 3] = (__bf16)(v[3] * r * g4.w);
}

// ---------------- RoPE on fused qkv (bf16, [M][3072]) ----------------
__global__ __launch_bounds__(512) void rope_kernel(__bf16* __restrict__ qkv,
                                                   const int* __restrict__ idx) {
    int m = blockIdx.x;
    int t = threadIdx.x;
    int h = t >> 5, j = t & 31;
    float pos = (float)idx[m];
    float inv = expf(-((float)(2 * j) / (float)HDD) * 9.210340371976184f);
    float ang = pos * inv;
    float c = cosf(ang), s = sinf(ang);
    long base = (long)m * 3072 + h * HDD + j;
    float x1 = (float)qkv[base], x2 = (float)qkv[base + 32];
    qkv[base] = (__bf16)(x1 * c - x2 * s);
    qkv[base + 32] = (__bf16)(x2 * c + x1 * s);
    long kbase = base + 1024;
    x1 = (float)qkv[kbase]; x2 = (float)qkv[kbase + 32];
    qkv[kbase] = (__bf16)(x1 * c - x2 * s);
    qkv[kbase + 32] = (__bf16)(x2 * c + x1 * s);
}

// ---------------- MFMA flash attention ----------------
// grid (qt=8, bh=64); 256 thr = 4 waves; wave w owns q rows [qt*64+w*16, +16)
__global__ __launch_bounds__(256) void attn_mfma(const __bf16* __restrict__ qkv,
                                                 __bf16* __restrict__ o) {
    int qt = blockIdx.x;
    int bh = blockIdx.y;
    int b = bh >> 4, h = bh & 15;
    int tid = threadIdx.x;
    int lane = tid & 63, w = tid >> 6;
    __shared__ __bf16 Ks[64 * APAD];
    __shared__ __bf16 Vt[64 * APAD];
    __shared__ __bf16 Ps[4][16 * APAD];

    int l15 = lane & 15, l4 = lane >> 4;
    int qrow0 = b * KSEL + qt * 64 + w * 16;
    bf16x8 qf[2];
    {
        long base = ((long)(qrow0 + l15)) * 3072 + h * 64 + l4 * 8;
        qf[0] = *(const bf16x8*)(qkv + base);
        qf[1] = *(const bf16x8*)(qkv + base + 32);
    }
    float m_run[4], l_run[4];
    f32x4 O[4];
#pragma unroll
    for (int r = 0; r < 4; ++r) { m_run[r] = -1e30f; l_run[r] = 0.f; }
    f32x4 zv = {0.f, 0.f, 0.f, 0.f};
#pragma unroll
    for (int ni = 0; ni < 4; ++ni) O[ni] = zv;

    int sr = tid & 63;        // staging row (k index)
    int sg = tid >> 6;        // staging dim group (16 dims)
    for (int kt = 0; kt <= qt; ++kt) {
        __syncthreads();
        long kvbase = ((long)(b * KSEL + kt * 64 + sr)) * 3072 + h * 64 + 1024;
        bf16x8 kv0 = *(const bf16x8*)(qkv + kvbase + sg * 16);
        bf16x8 kv1 = *(const bf16x8*)(qkv + kvbase + sg * 16 + 8);
        *(bf16x8*)(Ks + sr * APAD + sg * 16) = kv0;
        *(bf16x8*)(Ks + sr * APAD + sg * 16 + 8) = kv1;
        bf16x8 vv0 = *(const bf16x8*)(qkv + kvbase + 1024 + sg * 16);
        bf16x8 vv1 = *(const bf16x8*)(qkv + kvbase + 1024 + sg * 16 + 8);
#pragma unroll
        for (int i = 0; i < 8; ++i) {
            Vt[(sg * 16 + i) * APAD + sr] = vv0[i];
            Vt[(sg * 16 + 8 + i) * APAD + sr] = vv1[i];
        }
        __syncthreads();

        f32x4 S[4];
#pragma unroll
        for (int ni = 0; ni < 4; ++ni) S[ni] = zv;
#pragma unroll
        for (int ni = 0; ni < 4; ++ni) {
            bf16x8 kf0 = *(const bf16x8*)(Ks + (ni * 16 + l15) * APAD + l4 * 8);
            bf16x8 kf1 = *(const bf16x8*)(Ks + (ni * 16 + l15) * APAD + l4 * 8 + 32);
            S[ni] = __builtin_amdgcn_mfma_f32_16x16x32_bf16(qf[0], kf0, S[ni], 0, 0, 0);
            S[ni] = __builtin_amdgcn_mfma_f32_16x16x32_bf16(qf[1], kf1, S[ni], 0, 0, 0);
        }
        int rowb = qt * 64 + w * 16 + l4 * 4;
#pragma unroll
        for (int r = 0; r < 4; ++r) {
            float sv[4];
            float mx = -1e30f;
#pragma unroll
            for (int ni = 0; ni < 4; ++ni) {
                float x = S[ni][r] * 0.125f;
                int col = kt * 64 + ni * 16 + l15;
                if (col > rowb + r) x = -1e30f;
                sv[ni] = x;
                mx = fmaxf(mx, x);
            }
            mx = fmaxf(mx, __shfl_xor(mx, 1, 64));
            mx = fmaxf(mx, __shfl_xor(mx, 2, 64));
            mx = fmaxf(mx, __shfl_xor(mx, 4, 64));
            mx = fmaxf(mx, __shfl_xor(mx, 8, 64));
            float m_new = fmaxf(m_run[r], mx);
            float alpha = expf(m_run[r] - m_new);
            float ps = 0.f;
#pragma unroll
            for (int ni = 0; ni < 4; ++ni) {
                float e = expf(sv[ni] - m_new);
                sv[ni] = e;
                ps += e;
            }
            ps += __shfl_xor(ps, 1, 64);
            ps += __shfl_xor(ps, 2, 64);
            ps += __shfl_xor(ps, 4, 64);
            ps += __shfl_xor(ps, 8, 64);
            l_run[r] = l_run[r] * alpha + ps;
            m_run[r] = m_new;
#pragma unroll
            for (int ni = 0; ni < 4; ++ni) {
                O[ni][r] *= alpha;
                Ps[w][(l4 * 4 + r) * APAD + ni * 16 + l15] = (__bf16)sv[ni];
            }
        }
        // PV: A = P (wave-private LDS round-trip), B = Vt
#pragma unroll
        for (int ks = 0; ks < 2; ++ks) {
            bf16x8 pf = *(const bf16x8*)(Ps[w] + l15 * APAD + ks * 32 + l4 * 8);
#pragma unroll
            for (int ni = 0; ni < 4; ++ni) {
                bf16x8 vf = *(const bf16x8*)(Vt + (ni * 16 + l15) * APAD + ks * 32 + l4 * 8);
                O[ni] = __builtin_amdgcn_mfma_f32_16x16x32_bf16(pf, vf, O[ni], 0, 0, 0);
            }
        }
    }
    long orow = (long)(b * KSEL + qt * 64 + w * 16);
#pragma unroll
    for (int r = 0; r < 4; ++r) {
        float inv = 1.0f / l_run[r];
#pragma unroll
        for (int ni = 0; ni < 4; ++ni)
            o[(orow + l4 * 4 + r) * DD + h * 64 + ni * 16 + l15] = (__bf16)(O[ni][r] * inv);
    }
}

// ---------------- BCE losses ----------------
__global__ __launch_bounds__(256) void bce_kernel(const float* __restrict__ scores,
                                                  const float* __restrict__ logits,
                                                  const float* __restrict__ flags,
                                                  const float* __restrict__ fc2b,
                                                  float* __restrict__ acc) {
    int i = blockIdx.x * 256 + threadIdx.x;
    int tid = threadIdx.x;
    __shared__ float r0[256];
    __shared__ float r1[256];
    float tgt = flags[i];
    r0[tid] = bce_term(scores[i], tgt);
    r1[tid] = bce_term(logits[i] + fc2b[0], tgt);
    __syncthreads();
    for (int s2 = 128; s2 > 0; s2 >>= 1) {
        if (tid < s2) { r0[tid] += r0[tid + s2]; r1[tid] += r1[tid + s2]; }
        __syncthreads();
    }
    if (tid == 0) {
        atomicAdd(acc + 0, r0[0]);
        atomicAdd(acc + 1, r1[0]);
    }
}

__global__ void finalize_kernel(const float* __restrict__ acc, float* __restrict__ out) {
    out[0] = (acc[0] / (float)BT) * 0.01f + (acc[1] / (float)BT) * 0.01f;
}

extern "C" void kernel_launch(void* const* d_in, const int* in_sizes, int n_in,
                              void* d_out, int out_size, void* d_ws, size_t ws_size,
                              hipStream_t stream) {
    const float* hidden = (const float*)d_in[0];
    const float* router_w = (const float*)d_in[1];
    const float* fc1_w = (const float*)d_in[2];
    const float* fc1_b = (const float*)d_in[3];
    const float* fc2_w = (const float*)d_in[4];
    const float* fc2_b = (const float*)d_in[5];
    const float* ln1_g = (const float*)d_in[6];
    const float* ln2_g = (const float*)d_in[7];
    const float* wq = (const float*)d_in[8];
    const float* wk = (const float*)d_in[9];
    const float* wv = (const float*)d_in[10];
    const float* wo = (const float*)d_in[11];
    const float* w_gate = (const float*)d_in[12];
    const float* w_up = (const float*)d_in[13];
    const float* w_down = (const float*)d_in[14];

    float* out = (float*)d_out;
    char* wsb = (char*)d_ws;

    // ---- workspace layout (54.75 MiB total, proven available in R1/R2) ----
    float* scores = (float*)(wsb + 0x0);
    float* flags  = (float*)(wsb + 0x10000);
    float* logits = (float*)(wsb + 0x20000);
    int*   idx    = (int*)  (wsb + 0x30000);
    float* gate   = (float*)(wsb + 0x32000);
    float* acc    = (float*)(wsb + 0x34000);
    __bf16* fc1_t = (__bf16*)(wsb + 0x40000);     // [256][1024]   512 KB
    __bf16* wo_t  = (__bf16*)(wsb + 0xC0000);     // [1024][1024]  2 MB
    __bf16* w1    = (__bf16*)(wsb + 0x2C0000);    // 8 MB: wqkv_t / wd_t
    __bf16* wg_t  = (__bf16*)(wsb + 0xAC0000);    // [4096][1024]  8 MB
    __bf16* wu_t  = (__bf16*)(wsb + 0x12C0000);   // [4096][1024]  8 MB
    __bf16* a_bf  = (__bf16*)(wsb + 0x1AC0000);   // [2048][1024]  4 MB
    __bf16* qkv   = (__bf16*)(wsb + 0x1EC0000);   // [2048][3072] 12 MB
    __bf16* act_bf= (__bf16*)(wsb + 0x1AC0000);   // [2048][4096] 16 MB alias
    __bf16* att_bf= (__bf16*)(wsb + 0x2AC0000);   // [2048][1024]  4 MB
    __bf16* h_bf  = (__bf16*)(wsb + 0x2EC0000);   // [2048][1024]  4 MB
    __bf16* m_bf  = (__bf16*)(wsb + 0x32C0000);   // [2048][1024]  4 MB
    // hidden_bf [16384][1024] bf16 = 32 MB, aliases wg_t..qkv (all written later
    // in stream order than its last use in the predictor GEMM)
    __bf16* hidden_bf = (__bf16*)(wsb + 0xAC0000);

    __bf16* wqkv_t = w1;
    __bf16* wd_t   = w1;

    // 1. zero accumulators
    hipMemsetAsync(acc, 0, 2 * sizeof(float), stream);
    hipMemsetAsync(logits, 0, BT * sizeof(float), stream);

    // 2. fused passthrough copy + bf16 cast + router scores
    fused_pass<<<BT / 4, 256, 0, stream>>>(hidden, router_w, out, hidden_bf, scores);
    topk_kernel<<<BB, 1024, 0, stream>>>(scores, flags, idx, gate);

    // 3. predictor GEMM on bf16 hidden (fast global_load_lds path) + BCE
    castT_kernel<<<dim3(256 / 32, DD / 32), 256, 0, stream>>>(fc1_w, fc1_t, DD, 256);
    mfma_gemm<3><<<dim3(256 / 128, BT / 128), 256, 0, stream>>>(
        hidden_bf, fc1_t, BT, 256, DD, nullptr, nullptr, nullptr, nullptr, nullptr,
        nullptr, fc1_b, fc2_w, logits);
    bce_kernel<<<BT / 256, 256, 0, stream>>>(scores, logits, flags, fc2_b, acc);

    // 4. gather + rmsnorm1 -> a_bf
    rms_kernel<float><<<MTOK, 256, 0, stream>>>(hidden, idx, ln1_g, a_bf);

    // 5. fused qkv projection
    castT_kernel<<<dim3(DD / 32, DD / 32), 256, 0, stream>>>(wq, wqkv_t, DD, DD);
    castT_kernel<<<dim3(DD / 32, DD / 32), 256, 0, stream>>>(wk, wqkv_t + (size_t)1024 * 1024, DD, DD);
    castT_kernel<<<dim3(DD / 32, DD / 32), 256, 0, stream>>>(wv, wqkv_t + (size_t)2048 * 1024, DD, DD);
    mfma_gemm<0><<<dim3(3072 / 128, MTOK / 128), 256, 0, stream>>>(
        a_bf, wqkv_t, MTOK, 3072, DD, qkv, nullptr, nullptr, nullptr, nullptr,
        nullptr, nullptr, nullptr, nullptr);

    // 6. RoPE + MFMA flash attention
    rope_kernel<<<MTOK, 512, 0, stream>>>(qkv, idx);
    attn_mfma<<<dim3(KSEL / 64, BB * NHH), 256, 0, stream>>>(qkv, att_bf);

    // 7. Wo + residual -> h_bf
    castT_kernel<<<dim3(DD / 32, DD / 32), 256, 0, stream>>>(wo, wo_t, DD, DD);
    mfma_gemm<1><<<dim3(DD / 128, MTOK / 128), 256, 0, stream>>>(
        att_bf, wo_t, MTOK, DD, DD, h_bf, hidden, idx, nullptr, nullptr,
        nullptr, nullptr, nullptr, nullptr);

    // 8. rmsnorm2 -> m_bf
    rms_kernel<__bf16><<<MTOK, 256, 0, stream>>>(h_bf, nullptr, ln2_g, m_bf);

    // 9. fused SwiGLU gate/up -> act_bf
    castT_kernel<<<dim3(FF / 32, DD / 32), 256, 0, stream>>>(w_gate, wg_t, DD, FF);
    castT_kernel<<<dim3(FF / 32, DD / 32), 256, 0, stream>>>(w_up, wu_t, DD, FF);
    gateup_mfma<<<dim3(FF / 128, MTOK / 128), 256, 0, stream>>>(m_bf, wg_t, wu_t,
                                                                act_bf, MTOK, FF, DD);

    // 10. down proj + gated scatter into out
    castT_kernel<<<dim3(DD / 32, FF / 32), 256, 0, stream>>>(w_down, wd_t, FF, DD);
    mfma_gemm<2><<<dim3(DD / 128, MTOK / 128), 256, 0, stream>>>(
        act_bf, wd_t, MTOK, DD, FF, nullptr, hidden, idx, gate, h_bf, out,
        nullptr, nullptr, nullptr);

    // 11. aux scalar
    finalize_kernel<<<1, 1, 0, stream>>>(acc, out + (size_t)BT * DD);
}